// Round 1
// baseline (487.790 us; speedup 1.0000x reference)
//
#include <hip/hip_runtime.h>

#define G 4096
#define BSZ 2
#define NIN 8
#define HID 32
#define JS 8
#define ITILE 32
#define JTILE 32

__device__ __forceinline__ float elu1(float v) {
    return v > 0.f ? v : (__expf(v) - 1.f);
}

// h = elu(x @ W_infer + b_infer); s_src = h@We[:32], s_dst = h@We[32:]
__global__ void k_setup1(const float* __restrict__ x, const float* __restrict__ W,
                         const float* __restrict__ bias, const float* __restrict__ We,
                         float* __restrict__ h0, float* __restrict__ ssrc,
                         float* __restrict__ sdst) {
    int t = blockIdx.x * blockDim.x + threadIdx.x;
    if (t >= BSZ * G) return;
    float xin[NIN];
    const float* xp = x + t * NIN;
#pragma unroll
    for (int k = 0; k < NIN; k++) xin[k] = xp[k];
    float ss = 0.f, sd = 0.f;
    float* hp = h0 + t * HID;
#pragma unroll
    for (int o = 0; o < HID; o++) {
        float v = bias[o];
#pragma unroll
        for (int k = 0; k < NIN; k++) v += xin[k] * W[k * HID + o];
        v = elu1(v);
        hp[o] = v;
        ss += v * We[o];
        sd += v * We[HID + o];
    }
    ssrc[t] = ss;
    sdst[t] = sd;
}

// Main aggregation: partial recv_src + esum over a j-chunk, both batches per wg.
__global__ __launch_bounds__(256) void k_main(
    const float* __restrict__ h, const float* __restrict__ adj,
    const float* __restrict__ ssrc, const float* __restrict__ sdst,
    const float* __restrict__ bep, float coef, float* __restrict__ part) {
    __shared__ __align__(16) float e_s[BSZ][ITILE][36];  // [b][i][j], pad 36 (16B rows)
    __shared__ float h_s[BSZ][JTILE][33];                // [b][j][hh], pad 33
    int tid = threadIdx.x;
    int tg = tid >> 5, hh = tid & 31;
    int i0 = blockIdx.x * ITILE;
    int j0base = blockIdx.y * (G / JS);
    float be = bep[0];
    float acc[BSZ][4] = {};
    float esum[BSZ][4] = {};

    for (int jt = 0; jt < (G / JS / JTILE); jt++) {
        int j0 = j0base + jt * JTILE;
        // stage h tile: [b][jl][c]
#pragma unroll
        for (int r = 0; r < 8; r++) {
            int idx = r * 256 + tid;
            int b = idx >> 10, rem = idx & 1023, jl = rem >> 5, c = rem & 31;
            h_s[b][jl][c] = h[((size_t)((b << 12) + (j0 + jl))) * HID + c];
        }
        // compute e tile; thread covers (il = r*8+tg, jl = hh)
#pragma unroll
        for (int r = 0; r < 4; r++) {
            int il = r * 8 + tg;
            float adjv = adj[(size_t)(i0 + il) * G + (j0 + hh)];
            float w = (adjv == 0.f) ? coef : adjv;
#pragma unroll
            for (int b = 0; b < BSZ; b++) {
                float l = sdst[b * G + i0 + il] + ssrc[b * G + j0 + hh] + be;
                float sg = __builtin_amdgcn_rcpf(1.f + __expf(-l));
                float e = sg * w;
                e_s[b][il][hh] = e;
                esum[b][r] += e;
            }
        }
        __syncthreads();
        // accumulate: acc[b][k] (i = k*8+tg) over 32 j, h from LDS per (j,hh)
#pragma unroll
        for (int b = 0; b < BSZ; b++) {
#pragma unroll
            for (int j4 = 0; j4 < 8; j4++) {
                float hv0 = h_s[b][j4 * 4 + 0][hh];
                float hv1 = h_s[b][j4 * 4 + 1][hh];
                float hv2 = h_s[b][j4 * 4 + 2][hh];
                float hv3 = h_s[b][j4 * 4 + 3][hh];
#pragma unroll
                for (int k = 0; k < 4; k++) {
                    const float4 e4 = *(const float4*)&e_s[b][k * 8 + tg][j4 * 4];
                    acc[b][k] += e4.x * hv0;
                    acc[b][k] += e4.y * hv1;
                    acc[b][k] += e4.z * hv2;
                    acc[b][k] += e4.w * hv3;
                }
            }
        }
        __syncthreads();
    }

    int jsb = blockIdx.y;
#pragma unroll
    for (int b = 0; b < BSZ; b++) {
#pragma unroll
        for (int k = 0; k < 4; k++) {
            float v = esum[b][k];
#pragma unroll
            for (int m = 16; m; m >>= 1) v += __shfl_xor(v, m, 32);
            int i = i0 + k * 8 + tg;
            size_t base = ((size_t)(jsb * BSZ + b) * G + i) * 33;
            part[base + hh] = acc[b][k];
            if (hh == 0) part[base + 32] = v;
        }
    }
}

// Reduce partials; recv_dst = x_i*esum; node MLP + merge MLP (elu each).
__global__ __launch_bounds__(256) void k_post(
    const float* __restrict__ part, const float* __restrict__ hin,
    const float* __restrict__ Wn, const float* __restrict__ bn,
    const float* __restrict__ Wm, const float* __restrict__ bm,
    float* __restrict__ out) {
    __shared__ float rec[8][65];
    __shared__ float rec2[8][65];
    int tid = threadIdx.x;
    int rl = tid >> 5, hh = tid & 31;
    int row = blockIdx.x * 8 + rl;  // row = b*G + i
    int b = row >> 12, i = row & (G - 1);
    float rs = 0.f, es = 0.f;
#pragma unroll
    for (int js = 0; js < JS; js++) {
        size_t base = ((size_t)(js * BSZ + b) * G + i) * 33;
        rs += part[base + hh];
        es += part[base + 32];
    }
    float xv = hin[(size_t)row * HID + hh];
    rec[rl][hh] = rs;
    rec[rl][32 + hh] = xv * es;
    __syncthreads();
    float v = bn[hh];
#pragma unroll
    for (int k = 0; k < 64; k++) v += rec[rl][k] * Wn[k * HID + hh];
    v = elu1(v);
    rec2[rl][hh] = v;
    rec2[rl][32 + hh] = xv;
    __syncthreads();
    float u = bm[hh];
#pragma unroll
    for (int k = 0; k < 64; k++) u += rec2[rl][k] * Wm[k * HID + hh];
    out[(size_t)row * HID + hh] = elu1(u);
}

// BN stats per gene over (b, feature): 64 values -> mean, rstd
__global__ void k_bn(const float* __restrict__ h1, float* __restrict__ bnm,
                     float* __restrict__ bnr) {
    int tid = threadIdx.x;
    int gw = blockIdx.x * 4 + (tid >> 6);
    int t = tid & 63;
    int b = t >> 5, c = t & 31;
    float v = h1[((size_t)((b << 12) + gw)) * HID + c];
    float s = v, sq = v * v;
#pragma unroll
    for (int m = 32; m; m >>= 1) {
        s += __shfl_xor(s, m, 64);
        sq += __shfl_xor(sq, m, 64);
    }
    if (t == 0) {
        float mu = s * (1.f / 64.f);
        float var = sq * (1.f / 64.f) - mu * mu;
        bnm[gw] = mu;
        bnr[gw] = rsqrtf(var + 1e-5f);
    }
}

// apply BN, write h1n, compute s2 projections
__global__ void k_setup2(const float* __restrict__ h1, const float* __restrict__ bnm,
                         const float* __restrict__ bnr, const float* __restrict__ gamma,
                         const float* __restrict__ beta, const float* __restrict__ We,
                         float* __restrict__ h1n, float* __restrict__ ssrc,
                         float* __restrict__ sdst) {
    int t = blockIdx.x * blockDim.x + threadIdx.x;
    if (t >= BSZ * G) return;
    int g = t & (G - 1);
    float mu = bnm[g], r = bnr[g], ga = gamma[g], be = beta[g];
    float ss = 0.f, sd = 0.f;
#pragma unroll
    for (int o = 0; o < HID; o++) {
        float v = (h1[(size_t)t * HID + o] - mu) * r * ga + be;
        h1n[(size_t)t * HID + o] = v;
        ss += v * We[o];
        sd += v * We[HID + o];
    }
    ssrc[t] = ss;
    sdst[t] = sd;
}

extern "C" void kernel_launch(void* const* d_in, const int* in_sizes, int n_in,
                              void* d_out, int out_size, void* d_ws, size_t ws_size,
                              hipStream_t stream) {
    const float* x      = (const float*)d_in[0];
    const float* edges1 = (const float*)d_in[1];
    const float* edges2 = (const float*)d_in[2];
    const float* W_inf  = (const float*)d_in[3];
    const float* b_inf  = (const float*)d_in[4];
    const float* W_e1   = (const float*)d_in[5];
    const float* b_e1   = (const float*)d_in[6];
    const float* W_e2   = (const float*)d_in[7];
    const float* b_e2   = (const float*)d_in[8];
    const float* W_n1   = (const float*)d_in[9];
    const float* b_n1   = (const float*)d_in[10];
    const float* W_n2   = (const float*)d_in[11];
    const float* b_n2   = (const float*)d_in[12];
    const float* W_m1   = (const float*)d_in[13];
    const float* b_m1   = (const float*)d_in[14];
    const float* W_m2   = (const float*)d_in[15];
    const float* b_m2   = (const float*)d_in[16];
    const float* bn_g   = (const float*)d_in[17];
    const float* bn_b   = (const float*)d_in[18];
    float* out = (float*)d_out;

    float* ws = (float*)d_ws;
    float* h0   = ws;                    // 262144
    float* h1   = ws + 262144;           // 262144
    float* h1n  = ws + 524288;           // 262144
    float* s1s  = ws + 786432;           // 8192
    float* s1d  = ws + 794624;           // 8192
    float* s2s  = ws + 802816;           // 8192
    float* s2d  = ws + 811008;           // 8192
    float* bnm  = ws + 819200;           // 4096
    float* bnr  = ws + 823296;           // 4096
    float* part = ws + 827392;           // JS*2*4096*33 = 2162688

    const float ALPHA = 0.005f, BETA = 5e-5f;

    k_setup1<<<32, 256, 0, stream>>>(x, W_inf, b_inf, W_e1, h0, s1s, s1d);
    k_main<<<dim3(G / ITILE, JS), 256, 0, stream>>>(h0, edges1, s1s, s1d, b_e1, ALPHA, part);
    k_post<<<BSZ * G / 8, 256, 0, stream>>>(part, h0, W_n1, b_n1, W_m1, b_m1, h1);
    k_bn<<<G / 4, 256, 0, stream>>>(h1, bnm, bnr);
    k_setup2<<<32, 256, 0, stream>>>(h1, bnm, bnr, bn_g, bn_b, W_e2, h1n, s2s, s2d);
    k_main<<<dim3(G / ITILE, JS), 256, 0, stream>>>(h1n, edges2, s2s, s2d, b_e2, BETA, part);
    k_post<<<BSZ * G / 8, 256, 0, stream>>>(part, h1n, W_n2, b_n2, W_m2, b_m2, out);
}

// Round 2
// 240.910 us; speedup vs baseline: 2.0248x; 2.0248x over previous
//
#include <hip/hip_runtime.h>

#define G 4096
#define BSZ 2
#define NIN 8
#define HID 32
#define JS 8

typedef __attribute__((ext_vector_type(8))) short short8;
typedef __attribute__((ext_vector_type(4))) float floatx4;
typedef __attribute__((ext_vector_type(2))) short short2v;
typedef __attribute__((ext_vector_type(4))) short short4v;

__device__ __forceinline__ float elu1(float v) {
    return v > 0.f ? v : (__expf(v) - 1.f);
}
__device__ __forceinline__ unsigned short f2bf(float f) {
    unsigned u = __float_as_uint(f);
    u += 0x7fffu + ((u >> 16) & 1u);
    return (unsigned short)(u >> 16);
}

// h = elu(x@W_infer+b); s_src/s_dst projections; hT bf16 [b][c][g]
__global__ void k_setup1(const float* __restrict__ x, const float* __restrict__ W,
                         const float* __restrict__ bias, const float* __restrict__ We,
                         float* __restrict__ h0, unsigned short* __restrict__ hTb,
                         float* __restrict__ ssrc, float* __restrict__ sdst) {
    int t = blockIdx.x * blockDim.x + threadIdx.x;
    if (t >= BSZ * G) return;
    int b = t >> 12, g = t & (G - 1);
    float xin[NIN];
    const float* xp = x + t * NIN;
#pragma unroll
    for (int k = 0; k < NIN; k++) xin[k] = xp[k];
    float ss = 0.f, sd = 0.f;
    float* hp = h0 + (size_t)t * HID;
#pragma unroll
    for (int o = 0; o < HID; o++) {
        float v = bias[o];
#pragma unroll
        for (int k = 0; k < NIN; k++) v += xin[k] * W[k * HID + o];
        v = elu1(v);
        hp[o] = v;
        hTb[(size_t)(b * HID + o) * G + g] = f2bf(v);  // coalesced over g
        ss += v * We[o];
        sd += v * We[HID + o];
    }
    ssrc[t] = ss;
    sdst[t] = sd;
}

// MFMA aggregation: no LDS, no barriers. Wave w: b=w>>1, ihalf=w&1.
// A-frag (e): lane l holds rows m=l&15, k=(l>>4)*8+t  (computed in-register)
// B-frag (hT): lane l holds n=l&15, k=(l>>4)*8+t  (global dwordx4, L2-hit)
__global__ __launch_bounds__(256) void k_main(
    const float* __restrict__ adj, const float* __restrict__ ssrc,
    const float* __restrict__ sdst, const unsigned short* __restrict__ hTb,
    const float* __restrict__ bep, float coef, float* __restrict__ part) {
    int tid = threadIdx.x;
    int w = tid >> 6, l = tid & 63;
    int b = w >> 1, ihalf = w & 1;
    int i0 = blockIdx.x * 32;
    int jbase = blockIdx.y * (G / JS);
    int i = i0 + ihalf * 16 + (l & 15);
    int kg = l >> 4;
    float sd = sdst[b * G + i] + bep[0];
    floatx4 c0 = {0.f, 0.f, 0.f, 0.f}, c1 = {0.f, 0.f, 0.f, 0.f};
    float es = 0.f;
    const float* adjrow = adj + (size_t)i * G;
    const float* srow = ssrc + b * G;
    const unsigned short* hb0 = hTb + (size_t)(b * HID + (l & 15)) * G;
    const unsigned short* hb1 = hb0 + (size_t)16 * G;

    for (int jc = 0; jc < (G / JS / 32); jc++) {
        int j0 = jbase + jc * 32;
        int jme = j0 + kg * 8;
        float4 a0 = *(const float4*)(adjrow + jme);
        float4 a1 = *(const float4*)(adjrow + jme + 4);
        float4 s0 = *(const float4*)(srow + jme);
        float4 s1 = *(const float4*)(srow + jme + 4);
        float av[8] = {a0.x, a0.y, a0.z, a0.w, a1.x, a1.y, a1.z, a1.w};
        float sv[8] = {s0.x, s0.y, s0.z, s0.w, s1.x, s1.y, s1.z, s1.w};
        short8 af;
#pragma unroll
        for (int t = 0; t < 8; t++) {
            float wgt = (av[t] == 0.f) ? coef : av[t];
            float sg = __builtin_amdgcn_rcpf(1.f + __expf(-(sd + sv[t])));
            float e = sg * wgt;
            es += e;
            af[t] = (short)f2bf(e);
        }
        short8 bf0 = *(const short8*)(const void*)(hb0 + jme);
        short8 bf1 = *(const short8*)(const void*)(hb1 + jme);
        c0 = __builtin_amdgcn_mfma_f32_16x16x32_bf16(af, bf0, c0, 0, 0, 0);
        c1 = __builtin_amdgcn_mfma_f32_16x16x32_bf16(af, bf1, c1, 0, 0, 0);
    }
    // esum: reduce over kg groups (lanes ^16, ^32 share same i, b)
    es += __shfl_xor(es, 16);
    es += __shfl_xor(es, 32);
    size_t rb = ((size_t)(blockIdx.y * BSZ + b)) * G;
#pragma unroll
    for (int r = 0; r < 4; r++) {
        int row = i0 + ihalf * 16 + kg * 4 + r;  // C/D: row=(l>>4)*4+reg, col=l&15
        part[(rb + row) * 33 + (l & 15)] = c0[r];
        part[(rb + row) * 33 + 16 + (l & 15)] = c1[r];
    }
    if (l < 16) part[(rb + i) * 33 + 32] = es;
}

// Reduce partials; node+merge MLPs; optionally fused BN + We2 proj + hT write.
// Block: 8 genes (16 rows), 2 passes. Wave = one gene's 64 values in BN phase.
template <bool DO_BN>
__global__ __launch_bounds__(256) void k_post(
    const float* __restrict__ part, const float* __restrict__ hin,
    const float* __restrict__ Wn, const float* __restrict__ bn,
    const float* __restrict__ Wm, const float* __restrict__ bm,
    const float* __restrict__ gamma, const float* __restrict__ beta,
    const float* __restrict__ We2, float* __restrict__ outp,
    unsigned short* __restrict__ hTb, float* __restrict__ s2s,
    float* __restrict__ s2d) {
    __shared__ float Wns[64 * 32];
    __shared__ float Wms[64 * 32];
    __shared__ float rec[8][68];
    __shared__ float rec2[8][68];
    __shared__ unsigned short tb[BSZ][HID][8];
    int tid = threadIdx.x;
    int rl = tid >> 5, hh = tid & 31;
    int wv = tid >> 6;
#pragma unroll
    for (int r = 0; r < 8; r++) {
        Wns[r * 256 + tid] = Wn[r * 256 + tid];
        Wms[r * 256 + tid] = Wm[r * 256 + tid];
    }
    __syncthreads();
    int g0 = blockIdx.x * 8;
    for (int rp = 0; rp < 2; rp++) {
        int rr = rp * 8 + rl;
        int b = rr & 1;
        int g = g0 + (rr >> 1);
        int rowf = b * G + g;
        float rs = 0.f, es = 0.f;
#pragma unroll
        for (int js = 0; js < JS; js++) {
            size_t base = ((size_t)(js * BSZ + b) * G + g) * 33;
            rs += part[base + hh];
            es += part[base + 32];
        }
        float xv = hin[(size_t)rowf * HID + hh];
        if (rp) __syncthreads();
        rec[rl][hh] = rs;
        rec[rl][32 + hh] = xv * es;
        __syncthreads();
        float v = bn[hh];
#pragma unroll
        for (int k4 = 0; k4 < 16; k4++) {
            float4 r4 = *(const float4*)&rec[rl][k4 * 4];
            v += r4.x * Wns[(k4 * 4 + 0) * HID + hh];
            v += r4.y * Wns[(k4 * 4 + 1) * HID + hh];
            v += r4.z * Wns[(k4 * 4 + 2) * HID + hh];
            v += r4.w * Wns[(k4 * 4 + 3) * HID + hh];
        }
        v = elu1(v);
        rec2[rl][hh] = v;
        rec2[rl][32 + hh] = xv;
        __syncthreads();
        float u = bm[hh];
#pragma unroll
        for (int k4 = 0; k4 < 16; k4++) {
            float4 r4 = *(const float4*)&rec2[rl][k4 * 4];
            u += r4.x * Wms[(k4 * 4 + 0) * HID + hh];
            u += r4.y * Wms[(k4 * 4 + 1) * HID + hh];
            u += r4.z * Wms[(k4 * 4 + 2) * HID + hh];
            u += r4.w * Wms[(k4 * 4 + 3) * HID + hh];
        }
        float h1v = elu1(u);
        if (!DO_BN) {
            outp[(size_t)rowf * HID + hh] = h1v;
        } else {
            // wave holds gene g's 64 values: b = lane>>5, feature = lane&31
            float s = h1v, sq = h1v * h1v;
#pragma unroll
            for (int m = 32; m; m >>= 1) {
                s += __shfl_xor(s, m);
                sq += __shfl_xor(sq, m);
            }
            float mu = s * (1.f / 64.f);
            float var = sq * (1.f / 64.f) - mu * mu;
            float rstd = rsqrtf(var + 1e-5f);
            float hn = (h1v - mu) * rstd * gamma[g] + beta[g];
            outp[(size_t)rowf * HID + hh] = hn;
            tb[b][hh][rp * 4 + wv] = f2bf(hn);
            float ps = hn * We2[hh], pd = hn * We2[HID + hh];
#pragma unroll
            for (int m = 16; m; m >>= 1) {
                ps += __shfl_xor(ps, m);
                pd += __shfl_xor(pd, m);
            }
            if (hh == 0) {
                s2s[rowf] = ps;
                s2d[rowf] = pd;
            }
        }
    }
    if (DO_BN) {
        __syncthreads();
        // 2*32*8 = 512 bf16, 2 per thread, 4B stores
        int b2 = tid >> 7, c = (tid >> 2) & 31, g2 = (tid & 3) * 2;
        short2v val = *(const short2v*)&tb[b2][c][g2];
        *(short2v*)(void*)&hTb[(size_t)(b2 * HID + c) * G + g0 + g2] = val;
    }
}

extern "C" void kernel_launch(void* const* d_in, const int* in_sizes, int n_in,
                              void* d_out, int out_size, void* d_ws, size_t ws_size,
                              hipStream_t stream) {
    const float* x      = (const float*)d_in[0];
    const float* edges1 = (const float*)d_in[1];
    const float* edges2 = (const float*)d_in[2];
    const float* W_inf  = (const float*)d_in[3];
    const float* b_inf  = (const float*)d_in[4];
    const float* W_e1   = (const float*)d_in[5];
    const float* b_e1   = (const float*)d_in[6];
    const float* W_e2   = (const float*)d_in[7];
    const float* b_e2   = (const float*)d_in[8];
    const float* W_n1   = (const float*)d_in[9];
    const float* b_n1   = (const float*)d_in[10];
    const float* W_n2   = (const float*)d_in[11];
    const float* b_n2   = (const float*)d_in[12];
    const float* W_m1   = (const float*)d_in[13];
    const float* b_m1   = (const float*)d_in[14];
    const float* W_m2   = (const float*)d_in[15];
    const float* b_m2   = (const float*)d_in[16];
    const float* bn_g   = (const float*)d_in[17];
    const float* bn_b   = (const float*)d_in[18];
    float* out = (float*)d_out;

    float* ws = (float*)d_ws;
    float* h0   = ws;                        // 262144
    float* h1n  = ws + 262144;               // 262144
    float* s1s  = ws + 524288;               // 8192
    float* s1d  = ws + 532480;               // 8192
    float* s2s  = ws + 540672;               // 8192
    float* s2d  = ws + 548864;               // 8192
    float* part = ws + 557056;               // 8*2*4096*33 = 2162688
    unsigned short* hTb = (unsigned short*)(ws + 2719744);  // 262144 bf16

    const float ALPHA = 0.005f, BETA = 5e-5f;

    k_setup1<<<32, 256, 0, stream>>>(x, W_inf, b_inf, W_e1, h0, hTb, s1s, s1d);
    k_main<<<dim3(G / 32, JS), 256, 0, stream>>>(edges1, s1s, s1d, hTb, b_e1, ALPHA, part);
    k_post<true><<<G / 8, 256, 0, stream>>>(part, h0, W_n1, b_n1, W_m1, b_m1,
                                            bn_g, bn_b, W_e2, h1n, hTb, s2s, s2d);
    k_main<<<dim3(G / 32, JS), 256, 0, stream>>>(edges2, s2s, s2d, hTb, b_e2, BETA, part);
    k_post<false><<<G / 8, 256, 0, stream>>>(part, h1n, W_n2, b_n2, W_m2, b_m2,
                                             nullptr, nullptr, nullptr, out,
                                             nullptr, nullptr, nullptr);
}